// Round 12
// baseline (452.362 us; speedup 1.0000x reference)
//
#include <hip/hip_runtime.h>
#include <math.h>

#define NN 100000
#define NE 1600000
#define D 64
#define NG 2000
#define LN_EPS 1e-5f
#define NB ((NN + 255) / 256)        // 391 buckets of 256 nodes
#define NBK NB
#define NTILE ((NN + 63) / 64)       // 1563
#define EPB 6400                     // edges per partition block (250 blocks)
#define LSTR 72                      // padded LDS row stride (shorts), 144B = 9*16
#define WFRAG_MLP 24576              // 3 layers * 2 mats * 4096
#define WFRAG_TOT 26624              // + gate 2048

typedef __attribute__((ext_vector_type(8))) short short8;   // 8 bf16 in 4 VGPRs
typedef __attribute__((ext_vector_type(4))) float floatx4;  // MFMA accumulator

__device__ __forceinline__ unsigned short f2bf(float f) {
    unsigned int u = __float_as_uint(f);
    u += 0x7FFF + ((u >> 16) & 1);   // round-to-nearest-even
    return (unsigned short)(u >> 16);
}
__device__ __forceinline__ float bfu2f(unsigned short v) {
    return __uint_as_float(((unsigned int)v) << 16);
}

// ================= weight prep: fragment-major bf16 =================
__global__ __launch_bounds__(256) void k_wprep(const float* __restrict__ W1,
                                               const float* __restrict__ W2,
                                               const float* __restrict__ gw1,
                                               unsigned short* __restrict__ wfrag) {
    int idx = blockIdx.x * 256 + threadIdx.x;
    if (idx < WFRAG_MLP) {
        int l = idx / 8192;
        int rem = idx % 8192;
        int mat = rem / 4096;
        int r2 = rem % 4096;
        int ks = r2 / 2048;
        int c = (r2 / 512) % 4;
        int lane = (r2 / 8) % 64;
        int j = r2 % 8;
        int n = lane & 15, q = lane >> 4;
        int k = ks * 32 + q * 8 + j;
        int col = c * 16 + n;
        const float* Wm = mat ? W2 : W1;
        wfrag[idx] = f2bf(Wm[l * 4096 + k * 64 + col]);
    } else if (idx < WFRAG_TOT) {
        int g = idx - WFRAG_MLP;
        int ks = g / 1024;
        int c = (g / 512) % 2;
        int lane = (g / 8) % 64;
        int j = g % 8;
        int n = lane & 15, q = lane >> 4;
        int k = ks * 32 + q * 8 + j;
        wfrag[idx] = f2bf(gw1[k * 32 + c * 16 + n]);
    }
}

// ================= bucket totals (LDS histogram) =================
__global__ __launch_bounds__(256) void k_bcount(const int* __restrict__ dst,
                                                int* __restrict__ btot) {
    __shared__ int lcnt[NBK];
    int e0 = blockIdx.x * EPB;
    int tid = threadIdx.x;
    for (int i = tid; i < NBK; i += 256) lcnt[i] = 0;
    __syncthreads();
    for (int k = 0; k < EPB; k += 256)
        atomicAdd(&lcnt[dst[e0 + k + tid] >> 8], 1);
    __syncthreads();
    for (int i = tid; i < NBK; i += 256) {
        int c = lcnt[i];
        if (c) atomicAdd(&btot[i], c);
    }
}

// ========== scan 391 bucket totals -> bbase[NB+1], init bcur, sentinel ==========
__global__ __launch_bounds__(512) void k_bscan(const int* __restrict__ btot,
                                               int* __restrict__ bbase,
                                               int* __restrict__ bcur,
                                               int* __restrict__ row_ptr) {
    __shared__ int s[512];
    int t = threadIdx.x;
    int v = (t < NB) ? btot[t] : 0;
    s[t] = v;
    __syncthreads();
    for (int off = 1; off < 512; off <<= 1) {
        int u = (t >= off) ? s[t - off] : 0;
        __syncthreads();
        s[t] += u;
        __syncthreads();
    }
    if (t < NB) {
        bbase[t] = s[t] - v;
        bcur[t * 16] = s[t] - v;
    }
    if (t == NB - 1) bbase[NB] = s[t];
    if (t == 0) row_ptr[NN] = NE;
}

// phase B: block-local two-pass partition into bucket-major tmp.
__global__ __launch_bounds__(256) void k_part(const int* __restrict__ src,
                                              const int* __restrict__ dst,
                                              int* __restrict__ bcur,
                                              unsigned int* __restrict__ tmp) {
    __shared__ int lcnt[NBK];
    __shared__ int lbase[NBK];
    __shared__ int sd[EPB];
    __shared__ int ss[EPB];
    int e0 = blockIdx.x * EPB;
    int tid = threadIdx.x;

    for (int i = tid; i < NBK; i += 256) lcnt[i] = 0;
    __syncthreads();

    for (int k = 0; k < EPB; k += 256) {
        int d = dst[e0 + k + tid];
        int s = src[e0 + k + tid];
        sd[k + tid] = d;
        ss[k + tid] = s;
        atomicAdd(&lcnt[d >> 8], 1);
    }
    __syncthreads();

    for (int i = tid; i < NBK; i += 256) {
        int c = lcnt[i];
        lbase[i] = c ? atomicAdd(&bcur[i * 16], c) : 0;
        lcnt[i] = 0;
    }
    __syncthreads();

    for (int k = 0; k < EPB; k += 256) {
        int d = sd[k + tid];
        int s = ss[k + tid];
        int b = d >> 8;
        int pos = lbase[b] + atomicAdd(&lcnt[b], 1);
        tmp[pos] = ((unsigned int)s << 8) | (unsigned int)(d & 255);
    }
}

// phase C: per-bucket node histogram + scan -> row_ptr, then col fill.
__global__ __launch_bounds__(256) void k_bfill(const unsigned int* __restrict__ tmp,
                                               const int* __restrict__ bbase,
                                               int* __restrict__ row_ptr,
                                               int* __restrict__ col) {
    __shared__ int lcur[256];
    __shared__ int wsum[4];
    int b = blockIdx.x;
    int nb0 = b * 256;
    int nodes = min(256, NN - nb0);
    int tid = threadIdx.x;
    int lane = tid & 63;
    int w = tid >> 6;
    int estart = bbase[b], eend = bbase[b + 1];

    lcur[tid] = 0;
    __syncthreads();
    for (int e = estart + tid; e < eend; e += 256)
        atomicAdd(&lcur[tmp[e] & 255], 1);
    __syncthreads();

    int v = lcur[tid];
    int x = v;
#pragma unroll
    for (int off = 1; off < 64; off <<= 1) {
        int u = __shfl_up(x, off, 64);
        if (lane >= off) x += u;
    }
    if (lane == 63) wsum[w] = x;
    __syncthreads();
    int base = estart;
    for (int k = 0; k < w; k++) base += wsum[k];
    int rp = base + x - v;
    if (tid < nodes) row_ptr[nb0 + tid] = rp;
    lcur[tid] = rp;
    __syncthreads();

    for (int e = estart + tid; e < eend; e += 256) {
        unsigned int p = tmp[e];
        int pos = atomicAdd(&lcur[p & 255], 1);
        col[pos] = (int)(p >> 8);
    }
}

// ========== fused layer: gather + GIN + MFMA MLP + LN (+ gate on last) ==========
// block = 4 waves = one 64-node tile; wave owns 16 nodes (wave-private LDS h).
// Gather: 4 sub-iters x 4 node-groups x 16 lanes (lane owns 4 feats).
// MFMA layouts (gfx950 16x16x32 bf16): A[m=lane&15][k=q*8+j],
//   B[k=q*8+j][n=lane&15], C/D col=lane&15, row=q*4+reg.
template <int FIRST, int LAST>
__global__ __launch_bounds__(256) void k_layer(const float* __restrict__ xf32,
                                               const unsigned short* __restrict__ xbf,
                                               unsigned short* __restrict__ xout,
                                               const int* __restrict__ row_ptr,
                                               const int* __restrict__ col,
                                               const float* __restrict__ epsp,
                                               const short8* __restrict__ wf,
                                               const short8* __restrict__ gf,
                                               const float* __restrict__ b1,
                                               const float* __restrict__ b2,
                                               const float* __restrict__ lng,
                                               const float* __restrict__ lnb,
                                               const float* __restrict__ gb1,
                                               const float* __restrict__ gw2,
                                               const float* __restrict__ gb2,
                                               float* __restrict__ gate) {
    __shared__ __align__(16) unsigned short a2[4][16 * LSTR];
    int w = threadIdx.x >> 6;
    int lane = threadIdx.x & 63;
    int n = lane & 15;
    int q = lane >> 4;
    int g = q;                 // node-group within wave (gather phase)
    int fl = n;                // feature-lane (feats fl*4..fl*4+3)
    int base = blockIdx.x * 64 + w * 16;
    unsigned short* aw = a2[w];

    float ev = 1.0f + *epsp;

    // ---- gather phase: 16 nodes per wave, h -> wave-private LDS ----
    for (int sub = 0; sub < 4; sub++) {
        int node = base + sub * 4 + g;
        int nc = min(node, NN - 1);
        int start = row_ptr[nc], end = row_ptr[nc + 1];

        float4 A0 = {0, 0, 0, 0}, A1 = {0, 0, 0, 0}, A2 = {0, 0, 0, 0}, A3 = {0, 0, 0, 0};
        int eb = start;
        for (; eb + 16 <= end; eb += 16) {
            int c = col[eb + fl];
            if (FIRST) {
#pragma unroll
                for (int half = 0; half < 2; half++) {
                    float4 v[8];
#pragma unroll
                    for (int j = 0; j < 8; j++) {
                        int idx = __shfl(c, g * 16 + half * 8 + j, 64);
                        v[j] = *(const float4*)(xf32 + ((size_t)idx << 6) + fl * 4);
                    }
#pragma unroll
                    for (int j = 0; j < 8; j += 4) {
                        A0.x += v[j].x;   A0.y += v[j].y;   A0.z += v[j].z;   A0.w += v[j].w;
                        A1.x += v[j+1].x; A1.y += v[j+1].y; A1.z += v[j+1].z; A1.w += v[j+1].w;
                        A2.x += v[j+2].x; A2.y += v[j+2].y; A2.z += v[j+2].z; A2.w += v[j+2].w;
                        A3.x += v[j+3].x; A3.y += v[j+3].y; A3.z += v[j+3].z; A3.w += v[j+3].w;
                    }
                }
            } else {
                ushort4 v[16];
#pragma unroll
                for (int j = 0; j < 16; j++) {
                    int idx = __shfl(c, g * 16 + j, 64);
                    v[j] = *(const ushort4*)(xbf + ((size_t)idx << 6) + fl * 4);
                }
#pragma unroll
                for (int j = 0; j < 16; j += 4) {
                    A0.x += bfu2f(v[j].x);   A0.y += bfu2f(v[j].y);   A0.z += bfu2f(v[j].z);   A0.w += bfu2f(v[j].w);
                    A1.x += bfu2f(v[j+1].x); A1.y += bfu2f(v[j+1].y); A1.z += bfu2f(v[j+1].z); A1.w += bfu2f(v[j+1].w);
                    A2.x += bfu2f(v[j+2].x); A2.y += bfu2f(v[j+2].y); A2.z += bfu2f(v[j+2].z); A2.w += bfu2f(v[j+2].w);
                    A3.x += bfu2f(v[j+3].x); A3.y += bfu2f(v[j+3].y); A3.z += bfu2f(v[j+3].z); A3.w += bfu2f(v[j+3].w);
                }
            }
        }
        if (eb < end) {
            int cnt = end - eb;
            int c = (fl < cnt) ? col[eb + fl] : 0;
            for (int j = 0; j < cnt; j++) {
                int idx = __shfl(c, g * 16 + j, 64);
                if (FIRST) {
                    float4 v0 = *(const float4*)(xf32 + ((size_t)idx << 6) + fl * 4);
                    A0.x += v0.x; A0.y += v0.y; A0.z += v0.z; A0.w += v0.w;
                } else {
                    ushort4 v0 = *(const ushort4*)(xbf + ((size_t)idx << 6) + fl * 4);
                    A0.x += bfu2f(v0.x); A0.y += bfu2f(v0.y); A0.z += bfu2f(v0.z); A0.w += bfu2f(v0.w);
                }
            }
        }
        float sx, sy, sz, sw;
        if (FIRST) {
            float4 xs = *(const float4*)(xf32 + ((size_t)nc << 6) + fl * 4);
            sx = xs.x; sy = xs.y; sz = xs.z; sw = xs.w;
        } else {
            ushort4 xs = *(const ushort4*)(xbf + ((size_t)nc << 6) + fl * 4);
            sx = bfu2f(xs.x); sy = bfu2f(xs.y); sz = bfu2f(xs.z); sw = bfu2f(xs.w);
        }
        ushort4 o;
        o.x = f2bf(ev * sx + ((A0.x + A1.x) + (A2.x + A3.x)));
        o.y = f2bf(ev * sy + ((A0.y + A1.y) + (A2.y + A3.y)));
        o.z = f2bf(ev * sz + ((A0.z + A1.z) + (A2.z + A3.z)));
        o.w = f2bf(ev * sw + ((A0.w + A1.w) + (A2.w + A3.w)));
        *(ushort4*)(aw + (sub * 4 + g) * LSTR + fl * 4) = o;
    }

    // ---- weight B-fragments: vector 16B loads (fragment-major) ----
    short8 B1f[2][4], B2f[2][4];
#pragma unroll
    for (int ks = 0; ks < 2; ks++)
#pragma unroll
        for (int c = 0; c < 4; c++) {
            B1f[ks][c] = wf[(ks * 4 + c) * 64 + lane];
            B2f[ks][c] = wf[512 + (ks * 4 + c) * 64 + lane];
        }
    short8 B3f[2][2];
    if (LAST) {
#pragma unroll
        for (int ks = 0; ks < 2; ks++)
#pragma unroll
            for (int c = 0; c < 2; c++)
                B3f[ks][c] = gf[(ks * 2 + c) * 64 + lane];
    }

    float b1v[4], b2v[4], lgv[4], lbv[4];
#pragma unroll
    for (int c = 0; c < 4; c++) {
        b1v[c] = b1[c * 16 + n];
        b2v[c] = b2[c * 16 + n];
        lgv[c] = lng[c * 16 + n];
        lbv[c] = lnb[c * 16 + n];
    }
    float gb1v[2], gw2v[2], gb2v = 0.f;
    if (LAST) {
        gb1v[0] = gb1[n]; gb1v[1] = gb1[16 + n];
        gw2v[0] = gw2[n]; gw2v[1] = gw2[16 + n];
        gb2v = gb2[0];
    }

    // ---- A fragments from LDS h ----
    const short8* ap = (const short8*)(aw + n * LSTR);
    short8 A0 = ap[q];
    short8 A1 = ap[4 + q];

    // ---- GEMM1 ----
    floatx4 acc1[4];
#pragma unroll
    for (int c = 0; c < 4; c++) {
        floatx4 a = {b1v[c], b1v[c], b1v[c], b1v[c]};
        a = __builtin_amdgcn_mfma_f32_16x16x32_bf16(A0, B1f[0][c], a, 0, 0, 0);
        a = __builtin_amdgcn_mfma_f32_16x16x32_bf16(A1, B1f[1][c], a, 0, 0, 0);
        acc1[c] = a;
    }

    // ---- silu -> LDS (C-layout -> A-layout), padded stride ----
#pragma unroll
    for (int c = 0; c < 4; c++)
#pragma unroll
        for (int r = 0; r < 4; r++) {
            float v = acc1[c][r];
            v = v / (1.0f + __expf(-v));
            aw[(q * 4 + r) * LSTR + c * 16 + n] = f2bf(v);
        }

    short8 A20 = ap[q];
    short8 A21 = ap[4 + q];

    // ---- GEMM2 ----
    floatx4 acc2[4];
#pragma unroll
    for (int c = 0; c < 4; c++) {
        floatx4 a = {b2v[c], b2v[c], b2v[c], b2v[c]};
        a = __builtin_amdgcn_mfma_f32_16x16x32_bf16(A20, B2f[0][c], a, 0, 0, 0);
        a = __builtin_amdgcn_mfma_f32_16x16x32_bf16(A21, B2f[1][c], a, 0, 0, 0);
        acc2[c] = a;
    }

    // ---- LayerNorm ----
    float mu[4], inv[4];
#pragma unroll
    for (int r = 0; r < 4; r++) {
        float s = acc2[0][r] + acc2[1][r] + acc2[2][r] + acc2[3][r];
#pragma unroll
        for (int off = 1; off < 16; off <<= 1) s += __shfl_xor(s, off, 64);
        mu[r] = s * (1.0f / 64.0f);
        float d0 = acc2[0][r] - mu[r], d1 = acc2[1][r] - mu[r];
        float d2 = acc2[2][r] - mu[r], d3 = acc2[3][r] - mu[r];
        float vv = d0 * d0 + d1 * d1 + d2 * d2 + d3 * d3;
#pragma unroll
        for (int off = 1; off < 16; off <<= 1) vv += __shfl_xor(vv, off, 64);
        inv[r] = rsqrtf(vv * (1.0f / 64.0f) + LN_EPS);
    }

    // ---- store bf16 (+ stash for gate) ----
#pragma unroll
    for (int c = 0; c < 4; c++)
#pragma unroll
        for (int r = 0; r < 4; r++) {
            int node = base + q * 4 + r;
            float o = (acc2[c][r] - mu[r]) * inv[r] * lgv[c] + lbv[c];
            unsigned short ob = f2bf(o);
            if (node < NN) xout[((size_t)node << 6) + c * 16 + n] = ob;
            if (LAST) aw[(q * 4 + r) * LSTR + c * 16 + n] = ob;
        }

    // ---- fused gate MLP ----
    if (LAST) {
        short8 G0 = ap[q];
        short8 G1 = ap[4 + q];
        floatx4 acc3[2];
#pragma unroll
        for (int c = 0; c < 2; c++) {
            floatx4 a = {gb1v[c], gb1v[c], gb1v[c], gb1v[c]};
            a = __builtin_amdgcn_mfma_f32_16x16x32_bf16(G0, B3f[0][c], a, 0, 0, 0);
            a = __builtin_amdgcn_mfma_f32_16x16x32_bf16(G1, B3f[1][c], a, 0, 0, 0);
            acc3[c] = a;
        }
#pragma unroll
        for (int r = 0; r < 4; r++) {
            float v0 = acc3[0][r];
            v0 = v0 / (1.0f + __expf(-v0));
            float v1 = acc3[1][r];
            v1 = v1 / (1.0f + __expf(-v1));
            float gsum = v0 * gw2v[0] + v1 * gw2v[1];
#pragma unroll
            for (int off = 1; off < 16; off <<= 1) gsum += __shfl_xor(gsum, off, 64);
            int node = base + q * 4 + r;
            if (n == 0 && node < NN) gate[node] = gsum + gb2v;
        }
    }
}

// ================= per-graph softmax pooling =================
__global__ __launch_bounds__(256) void k_pool(const unsigned short* __restrict__ xf,
                                              const float* __restrict__ gate,
                                              const int* __restrict__ batch,
                                              float* __restrict__ out) {
    __shared__ float redm[4];
    __shared__ float reds[4];
    __shared__ float racc[4][D];
    int g = blockIdx.x;
    int w = threadIdx.x >> 6;
    int lane = threadIdx.x & 63;

    int lo = 0, hi = NN;
    while (lo < hi) { int mid = (lo + hi) >> 1; if (batch[mid] < g) lo = mid + 1; else hi = mid; }
    int start = lo;
    hi = NN;
    while (lo < hi) { int mid = (lo + hi) >> 1; if (batch[mid] < g + 1) lo = mid + 1; else hi = mid; }
    int end = lo;

    if (start >= end) {
        if (w == 0) out[((size_t)g << 6) + lane] = 0.0f;
        return;
    }

    float m = -INFINITY;
    for (int i = start + (int)threadIdx.x; i < end; i += 256) m = fmaxf(m, gate[i]);
#pragma unroll
    for (int mm = 32; mm >= 1; mm >>= 1) m = fmaxf(m, __shfl_xor(m, mm, 64));
    if (lane == 0) redm[w] = m;
    __syncthreads();
    m = fmaxf(fmaxf(redm[0], redm[1]), fmaxf(redm[2], redm[3]));

    float s = 0.0f;
    for (int i = start + (int)threadIdx.x; i < end; i += 256) s += __expf(gate[i] - m);
#pragma unroll
    for (int mm = 32; mm >= 1; mm >>= 1) s += __shfl_xor(s, mm, 64);
    if (lane == 0) reds[w] = s;
    __syncthreads();
    s = (reds[0] + reds[1]) + (reds[2] + reds[3]);

    float acc = 0.0f;
    for (int i = start + w; i < end; i += 4)
        acc += __expf(gate[i] - m) * bfu2f(xf[((size_t)i << 6) + lane]);
    racc[w][lane] = acc;
    __syncthreads();
    if (w == 0)
        out[((size_t)g << 6) + lane] =
            ((racc[0][lane] + racc[1][lane]) + (racc[2][lane] + racc[3][lane])) / s;
}

extern "C" void kernel_launch(void* const* d_in, const int* in_sizes, int n_in,
                              void* d_out, int out_size, void* d_ws, size_t ws_size,
                              hipStream_t stream) {
    const float* x   = (const float*)d_in[0];
    const int* ei    = (const int*)d_in[1];
    const int* batch = (const int*)d_in[2];
    const float* W1  = (const float*)d_in[3];
    const float* b1  = (const float*)d_in[4];
    const float* W2  = (const float*)d_in[5];
    const float* b2  = (const float*)d_in[6];
    const float* eps = (const float*)d_in[7];
    const float* lng = (const float*)d_in[8];
    const float* lnb = (const float*)d_in[9];
    const float* gw1 = (const float*)d_in[10];
    const float* gb1 = (const float*)d_in[11];
    const float* gw2 = (const float*)d_in[12];
    const float* gb2 = (const float*)d_in[13];

    const int* src = ei;
    const int* dst = ei + NE;

    // workspace layout (~39 MB)
    unsigned short* xa    = (unsigned short*)d_ws;              // NN*64 bf16 (ping)
    unsigned short* xbuf  = xa + (size_t)NN * D;                // NN*64 bf16 (pong)
    float* gate           = (float*)(xbuf + (size_t)NN * D);    // NN f32
    int* row_ptr          = (int*)(gate + NN);                  // NN+1
    int* col              = row_ptr + NN + 1;                   // NE
    unsigned int* tmp     = (unsigned int*)(col + NE);          // NE
    int* btot             = (int*)(tmp + NE);                   // NB
    int* bbase            = btot + NB;                          // NB+1
    int* bcur             = bbase + NB + 1;                     // NBK*16
    unsigned short* wfrag = (unsigned short*)(bcur + NBK * 16); // WFRAG_TOT

    float* out = (float*)d_out;

    // ---- prep + CSR build ----
    hipMemsetAsync(btot, 0, (size_t)NB * sizeof(int), stream);
    k_wprep<<<WFRAG_TOT / 256, 256, 0, stream>>>(W1, W2, gw1, wfrag);
    k_bcount<<<NE / EPB, 256, 0, stream>>>(dst, btot);
    k_bscan<<<1, 512, 0, stream>>>(btot, bbase, bcur, row_ptr);
    k_part<<<NE / EPB, 256, 0, stream>>>(src, dst, bcur, tmp);
    k_bfill<<<NBK, 256, 0, stream>>>(tmp, bbase, row_ptr, col);

    const short8* wf0 = (const short8*)(wfrag);
    const short8* wf1 = (const short8*)(wfrag + 8192);
    const short8* wf2 = (const short8*)(wfrag + 16384);
    const short8* gf  = (const short8*)(wfrag + WFRAG_MLP);

    // ---- 3 fused GIN layers: x(f32) -> xa -> xbuf -> xa ----
    k_layer<1, 0><<<NTILE, 256, 0, stream>>>(x, nullptr, xa, row_ptr, col, eps + 0,
        wf0, gf, b1 + 0 * D, b2 + 0 * D, lng + 0 * D, lnb + 0 * D, gb1, gw2, gb2, gate);
    k_layer<0, 0><<<NTILE, 256, 0, stream>>>(nullptr, xa, xbuf, row_ptr, col, eps + 1,
        wf1, gf, b1 + 1 * D, b2 + 1 * D, lng + 1 * D, lnb + 1 * D, gb1, gw2, gb2, gate);
    k_layer<0, 1><<<NTILE, 256, 0, stream>>>(nullptr, xbuf, xa, row_ptr, col, eps + 2,
        wf2, gf, b1 + 2 * D, b2 + 2 * D, lng + 2 * D, lnb + 2 * D, gb1, gw2, gb2, gate);

    k_pool<<<NG, 256, 0, stream>>>(xa, gate, batch, out);
}

// Round 13
// 314.445 us; speedup vs baseline: 1.4386x; 1.4386x over previous
//
#include <hip/hip_runtime.h>
#include <math.h>

#define NN 100000
#define NE 1600000
#define D 64
#define NG 2000
#define LN_EPS 1e-5f
#define NB ((NN + 255) / 256)        // 391 buckets of 256 nodes
#define NBK NB
#define NTILE ((NN + 63) / 64)       // 1563
#define EPB 6400                     // edges per partition block (250 blocks)
#define CAP 6144                     // bucket capacity (expected 4096, ~32 sigma slack)
#define LSTR 72                      // padded LDS row stride (shorts), 144B = 9*16
#define WFRAG_MLP 24576              // 3 layers * 2 mats * 4096
#define WFRAG_TOT 26624              // + gate 2048

typedef __attribute__((ext_vector_type(8))) short short8;   // 8 bf16 in 4 VGPRs
typedef __attribute__((ext_vector_type(4))) float floatx4;  // MFMA accumulator

__device__ __forceinline__ unsigned short f2bf(float f) {
    unsigned int u = __float_as_uint(f);
    u += 0x7FFF + ((u >> 16) & 1);   // round-to-nearest-even
    return (unsigned short)(u >> 16);
}
__device__ __forceinline__ float bfu2f(unsigned short v) {
    return __uint_as_float(((unsigned int)v) << 16);
}

// ================= fp32 -> bf16 feature convert =================
__global__ __launch_bounds__(256) void k_conv(const float* __restrict__ x,
                                              unsigned short* __restrict__ xb) {
    int i = blockIdx.x * 256 + threadIdx.x;
    xb[i] = f2bf(x[i]);
}

// ================= weight prep: fragment-major bf16 =================
__global__ __launch_bounds__(256) void k_wprep(const float* __restrict__ W1,
                                               const float* __restrict__ W2,
                                               const float* __restrict__ gw1,
                                               unsigned short* __restrict__ wfrag) {
    int idx = blockIdx.x * 256 + threadIdx.x;
    if (idx < WFRAG_MLP) {
        int l = idx / 8192;
        int rem = idx % 8192;
        int mat = rem / 4096;
        int r2 = rem % 4096;
        int ks = r2 / 2048;
        int c = (r2 / 512) % 4;
        int lane = (r2 / 8) % 64;
        int j = r2 % 8;
        int n = lane & 15, q = lane >> 4;
        int k = ks * 32 + q * 8 + j;
        int col = c * 16 + n;
        const float* Wm = mat ? W2 : W1;
        wfrag[idx] = f2bf(Wm[l * 4096 + k * 64 + col]);
    } else if (idx < WFRAG_TOT) {
        int g = idx - WFRAG_MLP;
        int ks = g / 1024;
        int c = (g / 512) % 2;
        int lane = (g / 8) % 64;
        int j = g % 8;
        int n = lane & 15, q = lane >> 4;
        int k = ks * 32 + q * 8 + j;
        wfrag[idx] = f2bf(gw1[k * 32 + c * 16 + n]);
    }
}

// ================= init bucket cursors (fixed-capacity, strided) =================
__global__ __launch_bounds__(512) void k_init(int* __restrict__ bcur) {
    int b = threadIdx.x;
    if (b < NBK) bcur[b * 16] = b * CAP;
}

// phase B: block-local two-pass partition into fixed-capacity bucket segments.
__global__ __launch_bounds__(256) void k_part(const int* __restrict__ src,
                                              const int* __restrict__ dst,
                                              int* __restrict__ bcur,
                                              unsigned int* __restrict__ colbuf) {
    __shared__ int lcnt[NBK];
    __shared__ int lbase[NBK];
    __shared__ int sd[EPB];
    __shared__ int ss[EPB];
    int e0 = blockIdx.x * EPB;
    int tid = threadIdx.x;

    for (int i = tid; i < NBK; i += 256) lcnt[i] = 0;
    __syncthreads();

    for (int k = 0; k < EPB; k += 256) {
        int d = dst[e0 + k + tid];
        int s = src[e0 + k + tid];
        sd[k + tid] = d;
        ss[k + tid] = s;
        atomicAdd(&lcnt[d >> 8], 1);
    }
    __syncthreads();

    for (int i = tid; i < NBK; i += 256) {
        int c = lcnt[i];
        lbase[i] = c ? atomicAdd(&bcur[i * 16], c) : 0;
        lcnt[i] = 0;
    }
    __syncthreads();

    for (int k = 0; k < EPB; k += 256) {
        int d = sd[k + tid];
        int s = ss[k + tid];
        int b = d >> 8;
        int pos = lbase[b] + atomicAdd(&lcnt[b], 1);
        colbuf[pos] = ((unsigned int)s << 8) | (unsigned int)(d & 255);
    }
}

// phase C: per-bucket (LDS-staged, in-place) histogram + scan -> row_start/row_end,
// then scatter col into the bucket's own strided segment.
__global__ __launch_bounds__(256) void k_bfill(unsigned int* __restrict__ colbuf,
                                               const int* __restrict__ bcur,
                                               int* __restrict__ rps,
                                               int* __restrict__ rpe) {
    __shared__ unsigned int sld[CAP];   // 24 KB bucket segment stage
    __shared__ int lcur[256];
    __shared__ int wsum[4];
    int b = blockIdx.x;
    int ebase = b * CAP;
    int cnt = bcur[b * 16] - ebase;
    int nb0 = b * 256;
    int nodes = min(256, NN - nb0);
    int tid = threadIdx.x;
    int lane = tid & 63;
    int w = tid >> 6;

    for (int e = tid; e < cnt; e += 256) sld[e] = colbuf[ebase + e];
    lcur[tid] = 0;
    __syncthreads();

    for (int e = tid; e < cnt; e += 256)
        atomicAdd(&lcur[sld[e] & 255], 1);
    __syncthreads();

    // block exclusive scan of 256 counts
    int v = lcur[tid];
    int x = v;
#pragma unroll
    for (int off = 1; off < 64; off <<= 1) {
        int u = __shfl_up(x, off, 64);
        if (lane >= off) x += u;
    }
    if (lane == 63) wsum[w] = x;
    __syncthreads();
    int base = ebase;
    for (int k = 0; k < w; k++) base += wsum[k];
    int rp = base + x - v;
    if (tid < nodes) {
        rps[nb0 + tid] = rp;
        rpe[nb0 + tid] = rp + v;
    }
    lcur[tid] = rp;
    __syncthreads();

    // scatter col within the (LDS-buffered) segment, in place
    for (int e = tid; e < cnt; e += 256) {
        unsigned int p = sld[e];
        int pos = atomicAdd(&lcur[p & 255], 1);
        colbuf[pos] = p >> 8;
    }
}

// ================= gather: h = (1+eps)x + sum_neighbors (bf16 in/out) =================
// 16 lanes per node, lane owns 4 feats; full 16-edge window unrolled (16 loads in flight)
__global__ __launch_bounds__(256) void k_gather(const unsigned short* __restrict__ xin,
                                                unsigned short* __restrict__ h,
                                                const int* __restrict__ rps,
                                                const int* __restrict__ rpe,
                                                const int* __restrict__ col,
                                                const float* __restrict__ epsp) {
    int w = threadIdx.x >> 6;
    int lane = threadIdx.x & 63;
    int g = lane >> 4;
    int fl = lane & 15;
    int node = (blockIdx.x * 4 + w) * 4 + g;
    int start = rps[node], end = rpe[node];

    float4 A0 = {0, 0, 0, 0}, A1 = {0, 0, 0, 0}, A2 = {0, 0, 0, 0}, A3 = {0, 0, 0, 0};
    int eb = start;
    for (; eb + 16 <= end; eb += 16) {
        int c = col[eb + fl];
        ushort4 v[16];
#pragma unroll
        for (int j = 0; j < 16; j++) {
            int idx = __shfl(c, g * 16 + j, 64);
            v[j] = *(const ushort4*)(xin + ((size_t)idx << 6) + fl * 4);
        }
#pragma unroll
        for (int j = 0; j < 16; j += 4) {
            A0.x += bfu2f(v[j].x); A0.y += bfu2f(v[j].y); A0.z += bfu2f(v[j].z); A0.w += bfu2f(v[j].w);
            A1.x += bfu2f(v[j+1].x); A1.y += bfu2f(v[j+1].y); A1.z += bfu2f(v[j+1].z); A1.w += bfu2f(v[j+1].w);
            A2.x += bfu2f(v[j+2].x); A2.y += bfu2f(v[j+2].y); A2.z += bfu2f(v[j+2].z); A2.w += bfu2f(v[j+2].w);
            A3.x += bfu2f(v[j+3].x); A3.y += bfu2f(v[j+3].y); A3.z += bfu2f(v[j+3].z); A3.w += bfu2f(v[j+3].w);
        }
    }
    if (eb < end) {
        int cnt = end - eb;
        int c = (fl < cnt) ? col[eb + fl] : 0;
        int j = 0;
        for (; j + 4 <= cnt; j += 4) {
            int i0 = __shfl(c, g * 16 + j, 64);
            int i1 = __shfl(c, g * 16 + j + 1, 64);
            int i2 = __shfl(c, g * 16 + j + 2, 64);
            int i3 = __shfl(c, g * 16 + j + 3, 64);
            ushort4 v0 = *(const ushort4*)(xin + ((size_t)i0 << 6) + fl * 4);
            ushort4 v1 = *(const ushort4*)(xin + ((size_t)i1 << 6) + fl * 4);
            ushort4 v2 = *(const ushort4*)(xin + ((size_t)i2 << 6) + fl * 4);
            ushort4 v3 = *(const ushort4*)(xin + ((size_t)i3 << 6) + fl * 4);
            A0.x += bfu2f(v0.x); A0.y += bfu2f(v0.y); A0.z += bfu2f(v0.z); A0.w += bfu2f(v0.w);
            A1.x += bfu2f(v1.x); A1.y += bfu2f(v1.y); A1.z += bfu2f(v1.z); A1.w += bfu2f(v1.w);
            A2.x += bfu2f(v2.x); A2.y += bfu2f(v2.y); A2.z += bfu2f(v2.z); A2.w += bfu2f(v2.w);
            A3.x += bfu2f(v3.x); A3.y += bfu2f(v3.y); A3.z += bfu2f(v3.z); A3.w += bfu2f(v3.w);
        }
        for (; j < cnt; j++) {
            int i0 = __shfl(c, g * 16 + j, 64);
            ushort4 v0 = *(const ushort4*)(xin + ((size_t)i0 << 6) + fl * 4);
            A0.x += bfu2f(v0.x); A0.y += bfu2f(v0.y); A0.z += bfu2f(v0.z); A0.w += bfu2f(v0.w);
        }
    }
    float ev = 1.0f + *epsp;
    ushort4 xs = *(const ushort4*)(xin + ((size_t)node << 6) + fl * 4);
    ushort4 o;
    o.x = f2bf(ev * bfu2f(xs.x) + ((A0.x + A1.x) + (A2.x + A3.x)));
    o.y = f2bf(ev * bfu2f(xs.y) + ((A0.y + A1.y) + (A2.y + A3.y)));
    o.z = f2bf(ev * bfu2f(xs.z) + ((A0.z + A1.z) + (A2.z + A3.z)));
    o.w = f2bf(ev * bfu2f(xs.w) + ((A0.w + A1.w) + (A2.w + A3.w)));
    *(ushort4*)(h + ((size_t)node << 6) + fl * 4) = o;
}

// ================= MFMA MLP + LN (+ fused gate on last layer) =================
// block = 4 waves = ONE 64-node tile (full grid for occupancy); wave owns 16 nodes.
template <int LAST>
__global__ __launch_bounds__(256) void k_mfma(const unsigned short* __restrict__ h,
                                              unsigned short* __restrict__ xout,
                                              const short8* __restrict__ wf,
                                              const short8* __restrict__ gf,
                                              const float* __restrict__ b1,
                                              const float* __restrict__ b2,
                                              const float* __restrict__ lng,
                                              const float* __restrict__ lnb,
                                              const float* __restrict__ gb1,
                                              const float* __restrict__ gw2,
                                              const float* __restrict__ gb2,
                                              float* __restrict__ gate) {
    __shared__ __align__(16) unsigned short a2[4][16 * LSTR];
    int w = threadIdx.x >> 6;
    int lane = threadIdx.x & 63;
    int n = lane & 15;
    int q = lane >> 4;
    int base = blockIdx.x * 64 + w * 16;

    short8 B1f[2][4], B2f[2][4];
#pragma unroll
    for (int ks = 0; ks < 2; ks++)
#pragma unroll
        for (int c = 0; c < 4; c++) {
            B1f[ks][c] = wf[(ks * 4 + c) * 64 + lane];
            B2f[ks][c] = wf[512 + (ks * 4 + c) * 64 + lane];
        }
    short8 B3f[2][2];
    if (LAST) {
#pragma unroll
        for (int ks = 0; ks < 2; ks++)
#pragma unroll
            for (int c = 0; c < 2; c++)
                B3f[ks][c] = gf[(ks * 2 + c) * 64 + lane];
    }

    float b1v[4], b2v[4], lgv[4], lbv[4];
#pragma unroll
    for (int c = 0; c < 4; c++) {
        b1v[c] = b1[c * 16 + n];
        b2v[c] = b2[c * 16 + n];
        lgv[c] = lng[c * 16 + n];
        lbv[c] = lnb[c * 16 + n];
    }
    float gb1v[2], gw2v[2], gb2v = 0.f;
    if (LAST) {
        gb1v[0] = gb1[n]; gb1v[1] = gb1[16 + n];
        gw2v[0] = gw2[n]; gw2v[1] = gw2[16 + n];
        gb2v = gb2[0];
    }

    unsigned short* aw = a2[w];

    int mnode = base + n;
    int mc = min(mnode, NN - 1);
    const short8* hp = (const short8*)(h + ((size_t)mc << 6));
    short8 A0 = hp[q];
    short8 A1 = hp[4 + q];

    floatx4 acc1[4];
#pragma unroll
    for (int c = 0; c < 4; c++) {
        floatx4 a = {b1v[c], b1v[c], b1v[c], b1v[c]};
        a = __builtin_amdgcn_mfma_f32_16x16x32_bf16(A0, B1f[0][c], a, 0, 0, 0);
        a = __builtin_amdgcn_mfma_f32_16x16x32_bf16(A1, B1f[1][c], a, 0, 0, 0);
        acc1[c] = a;
    }

#pragma unroll
    for (int c = 0; c < 4; c++)
#pragma unroll
        for (int r = 0; r < 4; r++) {
            float v = acc1[c][r];
            v = v / (1.0f + __expf(-v));
            aw[(q * 4 + r) * LSTR + c * 16 + n] = f2bf(v);
        }

    const short8* ap = (const short8*)(aw + n * LSTR);
    short8 A20 = ap[q];
    short8 A21 = ap[4 + q];

    floatx4 acc2[4];
#pragma unroll
    for (int c = 0; c < 4; c++) {
        floatx4 a = {b2v[c], b2v[c], b2v[c], b2v[c]};
        a = __builtin_amdgcn_mfma_f32_16x16x32_bf16(A20, B2f[0][c], a, 0, 0, 0);
        a = __builtin_amdgcn_mfma_f32_16x16x32_bf16(A21, B2f[1][c], a, 0, 0, 0);
        acc2[c] = a;
    }

    float mu[4], inv[4];
#pragma unroll
    for (int r = 0; r < 4; r++) {
        float s = acc2[0][r] + acc2[1][r] + acc2[2][r] + acc2[3][r];
#pragma unroll
        for (int off = 1; off < 16; off <<= 1) s += __shfl_xor(s, off, 64);
        mu[r] = s * (1.0f / 64.0f);
        float d0 = acc2[0][r] - mu[r], d1 = acc2[1][r] - mu[r];
        float d2 = acc2[2][r] - mu[r], d3 = acc2[3][r] - mu[r];
        float vv = d0 * d0 + d1 * d1 + d2 * d2 + d3 * d3;
#pragma unroll
        for (int off = 1; off < 16; off <<= 1) vv += __shfl_xor(vv, off, 64);
        inv[r] = rsqrtf(vv * (1.0f / 64.0f) + LN_EPS);
    }

#pragma unroll
    for (int c = 0; c < 4; c++)
#pragma unroll
        for (int r = 0; r < 4; r++) {
            int node = base + q * 4 + r;
            float o = (acc2[c][r] - mu[r]) * inv[r] * lgv[c] + lbv[c];
            unsigned short ob = f2bf(o);
            if (node < NN) xout[((size_t)node << 6) + c * 16 + n] = ob;
            if (LAST) aw[(q * 4 + r) * LSTR + c * 16 + n] = ob;
        }

    if (LAST) {
        short8 G0 = ap[q];
        short8 G1 = ap[4 + q];
        floatx4 acc3[2];
#pragma unroll
        for (int c = 0; c < 2; c++) {
            floatx4 a = {gb1v[c], gb1v[c], gb1v[c], gb1v[c]};
            a = __builtin_amdgcn_mfma_f32_16x16x32_bf16(G0, B3f[0][c], a, 0, 0, 0);
            a = __builtin_amdgcn_mfma_f32_16x16x32_bf16(G1, B3f[1][c], a, 0, 0, 0);
            acc3[c] = a;
        }
#pragma unroll
        for (int r = 0; r < 4; r++) {
            float v0 = acc3[0][r];
            v0 = v0 / (1.0f + __expf(-v0));
            float v1 = acc3[1][r];
            v1 = v1 / (1.0f + __expf(-v1));
            float gsum = v0 * gw2v[0] + v1 * gw2v[1];
#pragma unroll
            for (int off = 1; off < 16; off <<= 1) gsum += __shfl_xor(gsum, off, 64);
            int node = base + q * 4 + r;
            if (n == 0 && node < NN) gate[node] = gsum + gb2v;
        }
    }
}

// ================= per-graph softmax pooling =================
__global__ __launch_bounds__(256) void k_pool(const unsigned short* __restrict__ xf,
                                              const float* __restrict__ gate,
                                              const int* __restrict__ batch,
                                              float* __restrict__ out) {
    __shared__ float redm[4];
    __shared__ float reds[4];
    __shared__ float racc[4][D];
    int g = blockIdx.x;
    int w = threadIdx.x >> 6;
    int lane = threadIdx.x & 63;

    int lo = 0, hi = NN;
    while (lo < hi) { int mid = (lo + hi) >> 1; if (batch[mid] < g) lo = mid + 1; else hi = mid; }
    int start = lo;
    hi = NN;
    while (lo < hi) { int mid = (lo + hi) >> 1; if (batch[mid] < g + 1) lo = mid + 1; else hi = mid; }
    int end = lo;

    if (start >= end) {
        if (w == 0) out[((size_t)g << 6) + lane] = 0.0f;
        return;
    }

    float m = -INFINITY;
    for (int i = start + (int)threadIdx.x; i < end; i += 256) m = fmaxf(m, gate[i]);
#pragma unroll
    for (int mm = 32; mm >= 1; mm >>= 1) m = fmaxf(m, __shfl_xor(m, mm, 64));
    if (lane == 0) redm[w] = m;
    __syncthreads();
    m = fmaxf(fmaxf(redm[0], redm[1]), fmaxf(redm[2], redm[3]));

    float s = 0.0f;
    for (int i = start + (int)threadIdx.x; i < end; i += 256) s += __expf(gate[i] - m);
#pragma unroll
    for (int mm = 32; mm >= 1; mm >>= 1) s += __shfl_xor(s, mm, 64);
    if (lane == 0) reds[w] = s;
    __syncthreads();
    s = (reds[0] + reds[1]) + (reds[2] + reds[3]);

    float acc = 0.0f;
    for (int i = start + w; i < end; i += 4)
        acc += __expf(gate[i] - m) * bfu2f(xf[((size_t)i << 6) + lane]);
    racc[w][lane] = acc;
    __syncthreads();
    if (w == 0)
        out[((size_t)g << 6) + lane] =
            ((racc[0][lane] + racc[1][lane]) + (racc[2][lane] + racc[3][lane])) / s;
}

extern "C" void kernel_launch(void* const* d_in, const int* in_sizes, int n_in,
                              void* d_out, int out_size, void* d_ws, size_t ws_size,
                              hipStream_t stream) {
    const float* x   = (const float*)d_in[0];
    const int* ei    = (const int*)d_in[1];
    const int* batch = (const int*)d_in[2];
    const float* W1  = (const float*)d_in[3];
    const float* b1  = (const float*)d_in[4];
    const float* W2  = (const float*)d_in[5];
    const float* b2  = (const float*)d_in[6];
    const float* eps = (const float*)d_in[7];
    const float* lng = (const float*)d_in[8];
    const float* lnb = (const float*)d_in[9];
    const float* gw1 = (const float*)d_in[10];
    const float* gb1 = (const float*)d_in[11];
    const float* gw2 = (const float*)d_in[12];
    const float* gb2 = (const float*)d_in[13];

    const int* src = ei;
    const int* dst = ei + NE;

    // workspace layout (~36.5 MB)
    unsigned short* xb    = (unsigned short*)d_ws;              // NN*64 bf16 (ping)
    unsigned short* h     = xb + (size_t)NN * D;                // NN*64 bf16 (pong)
    float* gate           = (float*)(h + (size_t)NN * D);       // NN f32
    int* rps              = (int*)(gate + NN);                  // NN
    int* rpe              = rps + NN;                           // NN
    int* colbuf           = rpe + NN;                           // NBK*CAP (tmp, then col)
    int* bcur             = colbuf + (size_t)NBK * CAP;         // NBK*16
    unsigned short* wfrag = (unsigned short*)(bcur + NBK * 16); // WFRAG_TOT

    float* out = (float*)d_out;

    // ---- prep + CSR build (fixed-capacity buckets; no global histogram/scan) ----
    k_conv<<<(NN * D) / 256, 256, 0, stream>>>(x, xb);
    k_wprep<<<WFRAG_TOT / 256, 256, 0, stream>>>(W1, W2, gw1, wfrag);
    k_init<<<1, 512, 0, stream>>>(bcur);
    k_part<<<NE / EPB, 256, 0, stream>>>(src, dst, bcur, (unsigned int*)colbuf);
    k_bfill<<<NBK, 256, 0, stream>>>((unsigned int*)colbuf, bcur, rps, rpe);

    const short8* wf0 = (const short8*)(wfrag);
    const short8* wf1 = (const short8*)(wfrag + 8192);
    const short8* wf2 = (const short8*)(wfrag + 16384);
    const short8* gf  = (const short8*)(wfrag + WFRAG_MLP);

    // ---- 3 GIN layers (max-TLP gather + full-grid mfma, per round 11) ----
    k_gather<<<NN / 16, 256, 0, stream>>>(xb, h, rps, rpe, colbuf, eps + 0);
    k_mfma<0><<<NTILE, 256, 0, stream>>>(h, xb, wf0, gf,
        b1 + 0 * D, b2 + 0 * D, lng + 0 * D, lnb + 0 * D, gb1, gw2, gb2, gate);

    k_gather<<<NN / 16, 256, 0, stream>>>(xb, h, rps, rpe, colbuf, eps + 1);
    k_mfma<0><<<NTILE, 256, 0, stream>>>(h, xb, wf1, gf,
        b1 + 1 * D, b2 + 1 * D, lng + 1 * D, lnb + 1 * D, gb1, gw2, gb2, gate);

    k_gather<<<NN / 16, 256, 0, stream>>>(xb, h, rps, rpe, colbuf, eps + 2);
    k_mfma<1><<<NTILE, 256, 0, stream>>>(h, xb, wf2, gf,
        b1 + 2 * D, b2 + 2 * D, lng + 2 * D, lnb + 2 * D, gb1, gw2, gb2, gate);

    k_pool<<<NG, 256, 0, stream>>>(xb, gate, batch, out);
}